// Round 5
// baseline (68.704 us; speedup 1.0000x reference)
//
#include <hip/hip_runtime.h>

// Subtraction2: out[n, c*49 + kh*7 + kw, h, w] = x1[n,c,h,w] - x2[n,c,refl(h+kh-3),refl(w+kw-3)]
// N=8 C=64 H=W=56 K=7 PAD=3 -> h_out=w_out=56, x1c == x1.
// R3 post-mortem: load-instr cut was neutral -> byte-bound on fabric (reads ~184MB + writes 315MB).
// R4: block per (n,c); stage x1+x2 planes (25KB) in LDS once -> global reads = 12.8MB total.
//     Writes unchanged: 314.7MB, nt stores. Target = write ceiling ~6.9TB/s -> ~48us.

typedef float f4 __attribute__((ext_vector_type(4)));

constexpr int N_    = 8;
constexpr int C_    = 64;
constexpr int H_    = 56;
constexpr int W_    = 56;
constexpr int K_    = 7;
constexpr int PAD_  = 3;
constexpr int W4_   = W_ / 4;                  // 14
constexpr int HW_   = H_ * W_;                 // 3136 floats per plane
constexpr int PLANE4_ = HW_ / 4;               // 784 f4 per plane
constexpr int SITES_  = K_ * H_ * W4_;         // 5488 (kh,h,w4) sites per (n,c)
constexpr int TPB_  = 512;

__device__ __forceinline__ int refl(int i) {
    i = (i < 0) ? -i : i;
    return (i < H_) ? i : (2 * (H_ - 1) - i);
}

__global__ __launch_bounds__(TPB_)
void sub2_kernel(const float* __restrict__ x1,
                 const float* __restrict__ x2,
                 float* __restrict__ out)
{
    __shared__ float lds1[HW_];
    __shared__ float lds2[HW_];

    int nc  = blockIdx.x;                      // n*C_ + c
    int tid = threadIdx.x;

    const float* __restrict__ p1 = x1 + (size_t)nc * HW_;
    const float* __restrict__ p2 = x2 + (size_t)nc * HW_;

    // Stage both planes (each input byte read from global exactly once, grid-wide).
#pragma unroll
    for (int i = tid; i < PLANE4_; i += TPB_) {
        reinterpret_cast<f4*>(lds1)[i] = reinterpret_cast<const f4*>(p1)[i];
        reinterpret_cast<f4*>(lds2)[i] = reinterpret_cast<const f4*>(p2)[i];
    }
    __syncthreads();

    float* __restrict__ oplane = out + (size_t)nc * (K_ * K_) * HW_;

    constexpr int pL[10] = {3, 2, 1, 0, 1, 2, 3, 4, 5, 6};
    constexpr int pR[10] = {5, 6, 7, 8, 9, 10, 11, 10, 9, 8};

    for (int s = tid; s < SITES_; s += TPB_) {
        int w4 = s % W4_;
        int r  = s / W4_;
        int h  = r % H_;
        int kh = r / H_;

        int hs = refl(h + kh - PAD_);
        int w0 = w4 * 4;

        f4 a = *reinterpret_cast<const f4*>(lds1 + h * W_ + w0);

        // 12-float x2 window from LDS covering every reflected index this site needs.
        int wb = w0 - 4;
        wb = wb < 0 ? 0 : (wb > 44 ? 44 : wb);
        const float* xr = lds2 + hs * W_ + wb;
        f4 f0 = *reinterpret_cast<const f4*>(xr);
        f4 f1 = *reinterpret_cast<const f4*>(xr + 4);
        f4 f2 = *reinterpret_cast<const f4*>(xr + 8);
        float f[12] = {f0.x, f0.y, f0.z, f0.w, f1.x, f1.y, f1.z, f1.w,
                       f2.x, f2.y, f2.z, f2.w};

        bool eL = (w4 == 0);
        bool eR = (w4 == W4_ - 1);

        float b[10];
#pragma unroll
        for (int j = 0; j < 10; ++j)
            b[j] = eL ? f[pL[j]] : (eR ? f[pR[j]] : f[j + 1]);

        float* obase = oplane + (size_t)(kh * K_) * HW_ + h * W_ + w0;

#pragma unroll
        for (int kw = 0; kw < K_; ++kw) {
            f4 v;
            v.x = a.x - b[kw + 0];
            v.y = a.y - b[kw + 1];
            v.z = a.z - b[kw + 2];
            v.w = a.w - b[kw + 3];
            __builtin_nontemporal_store(v, reinterpret_cast<f4*>(obase + (size_t)kw * HW_));
        }
    }
}

extern "C" void kernel_launch(void* const* d_in, const int* in_sizes, int n_in,
                              void* d_out, int out_size, void* d_ws, size_t ws_size,
                              hipStream_t stream) {
    const float* x1 = (const float*)d_in[0];
    const float* x2 = (const float*)d_in[1];
    float* out = (float*)d_out;

    sub2_kernel<<<dim3(N_ * C_), TPB_, 0, stream>>>(x1, x2, out);
}

// Round 6
// 61.045 us; speedup vs baseline: 1.1255x; 1.1255x over previous
//
#include <hip/hip_runtime.h>

// Subtraction2: out[n, c*49 + kh*7 + kw, h, w] = x1[n,c,h,w] - x2[n,c,refl(h+kh-3),refl(w+kw-3)]
// N=8 C=64 H=W=56 K=7 PAD=3 -> h_out=w_out=56, x1c == x1.
// R3 = 62.1us (write 5.1 TB/s vs fill 6.9). R4 LDS staging regressed (68.7) -> not read-bound.
// R5: R3 body unchanged; 1D grid + bijective XCD-chunk swizzle so each XCD writes a
//     contiguous ~39MB region (write-stream locality at the memory controllers).

typedef float f4 __attribute__((ext_vector_type(4)));

constexpr int N_   = 8;
constexpr int C_   = 64;
constexpr int H_   = 56;
constexpr int W_   = 56;
constexpr int K_   = 7;
constexpr int PAD_ = 3;
constexpr int W4_  = W_ / 4;                 // 14
constexpr int TPC_ = K_ * H_ * W4_;          // threads per (n,c): 7*56*14 = 5488
constexpr int HW_  = H_ * W_;                // 3136 floats per plane
constexpr int BX_  = (TPC_ + 255) / 256;     // 22 blocks per (n,c)
constexpr int NBLK_ = BX_ * N_ * C_;         // 11264 (divisible by 8)
constexpr int NXCD_ = 8;
constexpr int CPX_  = NBLK_ / NXCD_;         // 1408

__device__ __forceinline__ int refl(int i) {
    i = (i < 0) ? -i : i;
    return (i < H_) ? i : (2 * (H_ - 1) - i);
}

__global__ __launch_bounds__(256)
void sub2_kernel(const float* __restrict__ x1,
                 const float* __restrict__ x2,
                 float* __restrict__ out)
{
    // XCD-chunk swizzle: consecutive hardware bids round-robin XCDs; give each XCD
    // a contiguous run of nc planes -> contiguous output region per XCD L2.
    int bid = blockIdx.x;
    int wg  = (bid & (NXCD_ - 1)) * CPX_ + (bid >> 3);
    int nc  = wg / BX_;                       // n*C_ + c
    int bx  = wg % BX_;

    int t = bx * 256 + threadIdx.x;
    if (t >= TPC_) return;

    // t = (kh*H_ + h)*W4_ + w4  (w4 fastest -> waves store contiguous 1KB lines)
    int w4 = t % W4_;
    int r  = t / W4_;
    int h  = r % H_;
    int kh = r / H_;

    int hs = refl(h + kh - PAD_);

    const float* __restrict__ x1row = x1 + ((size_t)nc * H_ + h) * W_;
    const float* __restrict__ x2row = x2 + ((size_t)nc * H_ + hs) * W_;

    int w0 = w4 * 4;
    f4 a = *reinterpret_cast<const f4*>(x1row + w0);

    // 12 contiguous floats covering every reflected index this thread needs.
    int wb = w0 - 4;
    wb = wb < 0 ? 0 : (wb > 44 ? 44 : wb);
    f4 f0 = *reinterpret_cast<const f4*>(x2row + wb);
    f4 f1 = *reinterpret_cast<const f4*>(x2row + wb + 4);
    f4 f2 = *reinterpret_cast<const f4*>(x2row + wb + 8);
    float f[12] = {f0.x, f0.y, f0.z, f0.w, f1.x, f1.y, f1.z, f1.w,
                   f2.x, f2.y, f2.z, f2.w};

    bool eL = (w4 == 0);
    bool eR = (w4 == W4_ - 1);

    // b[j] = x2row[refl(w0-3+j)], j = 0..9, compile-time-constant indices only.
    constexpr int pL[10] = {3, 2, 1, 0, 1, 2, 3, 4, 5, 6};
    constexpr int pR[10] = {5, 6, 7, 8, 9, 10, 11, 10, 9, 8};
    float b[10];
#pragma unroll
    for (int j = 0; j < 10; ++j)
        b[j] = eL ? f[pL[j]] : (eR ? f[pR[j]] : f[j + 1]);

    float* __restrict__ obase =
        out + (((size_t)nc * (K_ * K_) + kh * K_) * H_ + h) * W_ + w0;

#pragma unroll
    for (int kw = 0; kw < K_; ++kw) {
        f4 v;
        v.x = a.x - b[kw + 0];
        v.y = a.y - b[kw + 1];
        v.z = a.z - b[kw + 2];
        v.w = a.w - b[kw + 3];
        __builtin_nontemporal_store(v, reinterpret_cast<f4*>(obase + (size_t)kw * HW_));
    }
}

extern "C" void kernel_launch(void* const* d_in, const int* in_sizes, int n_in,
                              void* d_out, int out_size, void* d_ws, size_t ws_size,
                              hipStream_t stream) {
    const float* x1 = (const float*)d_in[0];
    const float* x2 = (const float*)d_in[1];
    float* out = (float*)d_out;

    sub2_kernel<<<dim3(NBLK_), 256, 0, stream>>>(x1, x2, out);
}

// Round 7
// 60.743 us; speedup vs baseline: 1.1311x; 1.0050x over previous
//
#include <hip/hip_runtime.h>

// Subtraction2: out[n, c*49 + kh*7 + kw, h, w] = x1[n,c,h,w] - x2[n,c,refl(h+kh-3),refl(w+kw-3)]
// N=8 C=64 H=W=56 K=7 PAD=3 -> h_out=w_out=56, x1c == x1.
// Ladder: R1 63.9 (kw-loop) -> R3 62.1 (window selects + nt) -> R4 LDS 68.7 (revert)
//         -> R5 61.0 (XCD swizzle, ~null). Writes 315MB @5.2TB/s vs fill 6.9TB/s.
// R6: single-variable A/B -- drop nontemporal stores (suspect: nt bypasses L2
//     write-combining; fill's 6.9TB/s uses normal writeback stores).

typedef float f4 __attribute__((ext_vector_type(4)));

constexpr int N_   = 8;
constexpr int C_   = 64;
constexpr int H_   = 56;
constexpr int W_   = 56;
constexpr int K_   = 7;
constexpr int PAD_ = 3;
constexpr int W4_  = W_ / 4;                 // 14
constexpr int TPC_ = K_ * H_ * W4_;          // threads per (n,c): 7*56*14 = 5488
constexpr int HW_  = H_ * W_;                // 3136 floats per plane
constexpr int BX_  = (TPC_ + 255) / 256;     // 22 blocks per (n,c)
constexpr int NBLK_ = BX_ * N_ * C_;         // 11264 (divisible by 8)
constexpr int NXCD_ = 8;
constexpr int CPX_  = NBLK_ / NXCD_;         // 1408

__device__ __forceinline__ int refl(int i) {
    i = (i < 0) ? -i : i;
    return (i < H_) ? i : (2 * (H_ - 1) - i);
}

__global__ __launch_bounds__(256)
void sub2_kernel(const float* __restrict__ x1,
                 const float* __restrict__ x2,
                 float* __restrict__ out)
{
    // XCD-chunk swizzle: each XCD owns a contiguous run of nc planes.
    int bid = blockIdx.x;
    int wg  = (bid & (NXCD_ - 1)) * CPX_ + (bid >> 3);
    int nc  = wg / BX_;                       // n*C_ + c
    int bx  = wg % BX_;

    int t = bx * 256 + threadIdx.x;
    if (t >= TPC_) return;

    // t = (kh*H_ + h)*W4_ + w4  (w4 fastest -> waves store contiguous 1KB lines)
    int w4 = t % W4_;
    int r  = t / W4_;
    int h  = r % H_;
    int kh = r / H_;

    int hs = refl(h + kh - PAD_);

    const float* __restrict__ x1row = x1 + ((size_t)nc * H_ + h) * W_;
    const float* __restrict__ x2row = x2 + ((size_t)nc * H_ + hs) * W_;

    int w0 = w4 * 4;
    f4 a = *reinterpret_cast<const f4*>(x1row + w0);

    // 12 contiguous floats covering every reflected index this thread needs.
    int wb = w0 - 4;
    wb = wb < 0 ? 0 : (wb > 44 ? 44 : wb);
    f4 f0 = *reinterpret_cast<const f4*>(x2row + wb);
    f4 f1 = *reinterpret_cast<const f4*>(x2row + wb + 4);
    f4 f2 = *reinterpret_cast<const f4*>(x2row + wb + 8);
    float f[12] = {f0.x, f0.y, f0.z, f0.w, f1.x, f1.y, f1.z, f1.w,
                   f2.x, f2.y, f2.z, f2.w};

    bool eL = (w4 == 0);
    bool eR = (w4 == W4_ - 1);

    // b[j] = x2row[refl(w0-3+j)], j = 0..9, compile-time-constant indices only.
    constexpr int pL[10] = {3, 2, 1, 0, 1, 2, 3, 4, 5, 6};
    constexpr int pR[10] = {5, 6, 7, 8, 9, 10, 11, 10, 9, 8};
    float b[10];
#pragma unroll
    for (int j = 0; j < 10; ++j)
        b[j] = eL ? f[pL[j]] : (eR ? f[pR[j]] : f[j + 1]);

    float* __restrict__ obase =
        out + (((size_t)nc * (K_ * K_) + kh * K_) * H_ + h) * W_ + w0;

#pragma unroll
    for (int kw = 0; kw < K_; ++kw) {
        f4 v;
        v.x = a.x - b[kw + 0];
        v.y = a.y - b[kw + 1];
        v.z = a.z - b[kw + 2];
        v.w = a.w - b[kw + 3];
        *reinterpret_cast<f4*>(obase + (size_t)kw * HW_) = v;
    }
}

extern "C" void kernel_launch(void* const* d_in, const int* in_sizes, int n_in,
                              void* d_out, int out_size, void* d_ws, size_t ws_size,
                              hipStream_t stream) {
    const float* x1 = (const float*)d_in[0];
    const float* x2 = (const float*)d_in[1];
    float* out = (float*)d_out;

    sub2_kernel<<<dim3(NBLK_), 256, 0, stream>>>(x1, x2, out);
}